// Round 1
// baseline (628.896 us; speedup 1.0000x reference)
//
#include <hip/hip_runtime.h>
#include <math.h>

// GakeModel: per-node masked-context log-softmax scoring.
// One 128-thread block per batch element; 3 contexts (K=64,64,16) processed
// sequentially through a padded LDS tile.

constexpr int D_ = 128;   // embedding dim
constexpr int R_ = 1000;  // relation table rows
constexpr int KN_ = 64, KP_ = 64, KE_ = 16;

struct Smem {
  float c[64][D_ + 1];      // padded: stride 129 words -> conflict-free row dots
  float S[D_];              // masked row-sum (incl. si)
  float si[D_];             // si embedding
  const float* rowp[64];    // per-context row pointers (nullptr = masked out)
  float red[8];             // block-reduce scratch
};

__device__ __forceinline__ float wadd(float v) {
#pragma unroll
  for (int off = 32; off > 0; off >>= 1) v += __shfl_down(v, off, 64);
  return v;  // lane 0 holds the wave sum
}
__device__ __forceinline__ float wmax(float v) {
#pragma unroll
  for (int off = 32; off > 0; off >>= 1) v = fmaxf(v, __shfl_down(v, off, 64));
  return v;
}

// Returns the context's log-p term. For ACC=true the value is valid on all
// threads; for ACC=false only thread 0's return value is meaningful (and only
// thread 0 consumes it).
template <int K, bool ACC>
__device__ float ctx_logp(Smem& sm, float si_d,
                          const float* __restrict__ ent,
                          const float* __restrict__ rel,
                          const int* __restrict__ ids,
                          const int* __restrict__ isrel,
                          const int* __restrict__ mask) {
  const int d = threadIdx.x;      // 0..127
  const int wid = d >> 6;

  __syncthreads();  // previous context done reading sm.* before we overwrite

  // Resolve row pointers once, coalesced (thread k handles entry k).
  if (d < K) {
    const float* p = nullptr;
    if (mask[d]) {
      const int id = ids[d];
      p = isrel[d] ? rel + (size_t)(id % R_) * D_ : ent + (size_t)id * D_;
    }
    sm.rowp[d] = p;
  }
  __syncthreads();

  // Stage rows (thread d owns dim d), accumulating masked sum + sq-norm.
  float sumS = si_d;
  float sq = si_d * si_d;
#pragma unroll 4
  for (int k = 0; k < K; ++k) {
    const float* p = sm.rowp[k];  // uniform across block -> uniform branch
    const float v = p ? p[d] : 0.f;
    sm.c[k][d] = v;
    sumS += v;
    sq += v * v;
  }
  sm.S[d] = sumS;

  const float wq = wadd(sq);
  if ((d & 63) == 0) sm.red[wid] = wq;
  __syncthreads();  // also publishes sm.c / sm.S (and sm.si on first call)
  const float invn = rsqrtf(sm.red[0] + sm.red[1]);

  // Scores: thread r owns row r (row 0 = si). Stride-129 LDS rows keep the
  // per-lane reads conflict-free; sm.S[j] is a same-address broadcast.
  float score = 0.f;
  bool valid = false;
  if (d <= K) {
    const float* row = (d == 0) ? sm.si : &sm.c[d - 1][0];
    float acc = 0.f;
#pragma unroll 16
    for (int j = 0; j < D_; ++j) acc += row[j] * sm.S[j];
    score = acc * invn;
    valid = (d == 0) || (sm.rowp[d - 1] != nullptr);
  }

  const float sv = valid ? score : -INFINITY;
  const float wm = wmax(sv);
  __syncthreads();  // all invn reads of red[0..1] done
  if ((d & 63) == 0) sm.red[wid] = wm;
  __syncthreads();
  const float mx = fmaxf(sm.red[0], sm.red[1]);

  const float e = valid ? expf(score - mx) : 0.f;
  const float ssv = valid ? score : 0.f;
  const float cv = valid ? 1.f : 0.f;
  const float we = wadd(e);
  const float ws = wadd(ssv);
  const float wc = wadd(cv);
  if ((d & 63) == 0) {
    sm.red[2 + wid] = we;
    sm.red[4 + wid] = ws;
    sm.red[6 + wid] = wc;
  }
  __syncthreads();
  const float logZ = logf(sm.red[2] + sm.red[3]);
  if (ACC) {
    const float sum_s = sm.red[4] + sm.red[5];
    const float V = sm.red[6] + sm.red[7];
    // sum over valid rows of (s - mx - logZ)
    return sum_s - V * (mx + logZ);
  } else {
    return score - mx - logZ;  // thread 0's row-0 value
  }
}

__global__ __launch_bounds__(128) void gake_kernel(
    const float* __restrict__ ent, const float* __restrict__ rel,
    const int* __restrict__ node_ids, const int* __restrict__ node_isrel,
    const int* __restrict__ nbr_ids, const int* __restrict__ nbr_isrel,
    const int* __restrict__ nbr_mask, const int* __restrict__ path_ids,
    const int* __restrict__ path_isrel, const int* __restrict__ path_mask,
    const int* __restrict__ edge_ids, const int* __restrict__ edge_isrel,
    const int* __restrict__ edge_mask, float* __restrict__ out) {
  __shared__ Smem sm;
  const int b = blockIdx.x;
  const int d = threadIdx.x;

  const int nid = node_ids[b];
  const float* srow = node_isrel[b] ? rel + (size_t)(nid % R_) * D_
                                    : ent + (size_t)nid * D_;
  const float si_d = srow[d];
  sm.si[d] = si_d;  // published by the sync inside the first ctx_logp

  const float ln = ctx_logp<KN_, true>(sm, si_d, ent, rel,
                                       nbr_ids + (size_t)b * KN_,
                                       nbr_isrel + (size_t)b * KN_,
                                       nbr_mask + (size_t)b * KN_);
  const float lp = ctx_logp<KP_, true>(sm, si_d, ent, rel,
                                       path_ids + (size_t)b * KP_,
                                       path_isrel + (size_t)b * KP_,
                                       path_mask + (size_t)b * KP_);
  const float le = ctx_logp<KE_, false>(sm, si_d, ent, rel,
                                        edge_ids + (size_t)b * KE_,
                                        edge_isrel + (size_t)b * KE_,
                                        edge_mask + (size_t)b * KE_);
  if (d == 0) out[b] = -(ln + 0.1f * lp + 0.1f * le);
}

extern "C" void kernel_launch(void* const* d_in, const int* in_sizes, int n_in,
                              void* d_out, int out_size, void* d_ws,
                              size_t ws_size, hipStream_t stream) {
  const float* ent = (const float*)d_in[0];
  const float* rel = (const float*)d_in[1];
  const int* node_ids = (const int*)d_in[2];
  const int* node_isrel = (const int*)d_in[3];
  const int* nbr_ids = (const int*)d_in[4];
  const int* nbr_isrel = (const int*)d_in[5];
  const int* nbr_mask = (const int*)d_in[6];
  const int* path_ids = (const int*)d_in[7];
  const int* path_isrel = (const int*)d_in[8];
  const int* path_mask = (const int*)d_in[9];
  const int* edge_ids = (const int*)d_in[10];
  const int* edge_isrel = (const int*)d_in[11];
  const int* edge_mask = (const int*)d_in[12];
  float* out = (float*)d_out;

  const int B = in_sizes[2];  // node_ids element count = batch
  gake_kernel<<<B, 128, 0, stream>>>(
      ent, rel, node_ids, node_isrel, nbr_ids, nbr_isrel, nbr_mask, path_ids,
      path_isrel, path_mask, edge_ids, edge_isrel, edge_mask, out);
}

// Round 2
// 618.537 us; speedup vs baseline: 1.0167x; 1.0167x over previous
//
#include <hip/hip_runtime.h>
#include <math.h>
#include <stdint.h>

// GakeModel: per-node masked-context log-softmax scoring.
// One 128-thread block per batch element; 3 contexts (K=64,64,16) processed
// sequentially through a bf16-packed padded LDS tile.
//
// Key decisions (R1 -> R2):
//  - bf16 row staging: LDS 34 KB -> 17.4 KB => 9 blocks/CU (vs 4).
//  - branch-free staging: masked rows load a hot dummy row (ent row 0) and
//    get cndmask'ed to 0 => unconditional, batchable global loads.
//  - address math from uniform scalar loads of ids/isrel/mask (no LDS rowp).
//  - S (row-sum), sq-norm, si kept in fp32; only the score dot uses bf16 rows.

constexpr int D_ = 128;   // embedding dim
constexpr int R_ = 1000;  // relation table rows
constexpr int KN_ = 64, KP_ = 64, KE_ = 16;
constexpr int ROWW = 65;  // uint32 words per staged row (64 data + 1 pad)
constexpr int NROWS = 65; // row 0 = si, rows 1..64 = context rows

struct Smem {
  uint32_t c[NROWS * ROWW + 1];  // +1 pad => S stays 8B-aligned (float2 reads)
  float S[D_];                   // masked row-sum incl. si (fp32)
  float red[8];                  // block-reduce scratch
};

__device__ __forceinline__ float wadd(float v) {
#pragma unroll
  for (int off = 32; off > 0; off >>= 1) v += __shfl_down(v, off, 64);
  return v;  // lane 0 holds the wave sum
}
__device__ __forceinline__ float wmax(float v) {
#pragma unroll
  for (int off = 32; off > 0; off >>= 1) v = fmaxf(v, __shfl_down(v, off, 64));
  return v;
}

__device__ __forceinline__ uint16_t f2bf(float v) {
  // round-to-nearest-even f32 -> bf16 (values are finite, no NaN handling)
  const uint32_t u = __float_as_uint(v);
  return (uint16_t)((u + 0x7fffu + ((u >> 16) & 1u)) >> 16);
}

// Returns the context's log-p term. ACC=true: valid on all threads.
// ACC=false: only thread 0's value is meaningful (row 0 = si).
template <int K, bool ACC>
__device__ float ctx_logp(Smem& sm, float si_d,
                          const float* __restrict__ ent,
                          const float* __restrict__ rel,
                          const int* __restrict__ ids,
                          const int* __restrict__ isrel,
                          const int* __restrict__ mask) {
  const int d = threadIdx.x;  // 0..127
  const int wid = d >> 6;
  uint16_t* ch = (uint16_t*)sm.c;

  __syncthreads();  // previous context's readers of c/S/red are done

  // Stage rows (thread d owns dim d). All control is block-uniform scalar;
  // masked entries load the always-hot dummy row (ent row 0) and are zeroed.
  float sumS = si_d;
  float sq = si_d * si_d;
#pragma unroll 16
  for (int k = 0; k < K; ++k) {
    const int m = mask[k];    // uniform -> scalar load
    const int id = ids[k];
    const float* p = m ? (isrel[k] ? rel + (size_t)(id % R_) * D_
                                   : ent + (size_t)id * D_)
                       : ent;  // dummy hot row, value discarded
    float v = p[d];
    v = m ? v : 0.f;
    ch[(k + 1) * (2 * ROWW) + d] = f2bf(v);
    sumS += v;
    sq += v * v;
  }
  sm.S[d] = sumS;

  const float wq = wadd(sq);
  if ((d & 63) == 0) sm.red[wid] = wq;
  __syncthreads();  // publishes c rows, S, red[0..1]
  const float invn = rsqrtf(sm.red[0] + sm.red[1]);

  // Scores: thread r owns row r (row 0 = si). Stride-65-word rows => bank
  // (r+jj)%32, 2-way aliasing only (free). S read is a same-address broadcast.
  float score = 0.f;
  bool valid = false;
  if (d <= K) {
    const uint32_t* row = sm.c + d * ROWW;
    const float2* S2 = (const float2*)sm.S;
    float acc = 0.f;
#pragma unroll
    for (int jj = 0; jj < D_ / 2; ++jj) {
      const uint32_t w = row[jj];
      const float2 s2 = S2[jj];
      acc += __uint_as_float(w << 16) * s2.x;       // dim 2*jj
      acc += __uint_as_float(w & 0xffff0000u) * s2.y;  // dim 2*jj+1
    }
    score = acc * invn;
    valid = (d == 0) || (mask[d - 1] != 0);
  }

  const float sv = valid ? score : -INFINITY;
  const float wm = wmax(sv);
  __syncthreads();  // all invn reads of red[0..1] complete
  if ((d & 63) == 0) sm.red[wid] = wm;
  __syncthreads();
  const float mx = fmaxf(sm.red[0], sm.red[1]);

  const float e = valid ? __expf(score - mx) : 0.f;
  const float we = wadd(e);
  const float ws = wadd(valid ? score : 0.f);
  const float wc = wadd(valid ? 1.f : 0.f);
  if ((d & 63) == 0) {
    sm.red[2 + wid] = we;   // distinct slots from red[0..1] -> no sync needed
    sm.red[4 + wid] = ws;
    sm.red[6 + wid] = wc;
  }
  __syncthreads();
  const float logZ = __logf(sm.red[2] + sm.red[3]);
  if (ACC) {
    const float sum_s = sm.red[4] + sm.red[5];
    const float V = sm.red[6] + sm.red[7];
    return sum_s - V * (mx + logZ);  // sum over valid rows of (s - mx - logZ)
  } else {
    return score - mx - logZ;  // thread 0 holds row 0's score
  }
}

__global__ __launch_bounds__(128, 4) void gake_kernel(
    const float* __restrict__ ent, const float* __restrict__ rel,
    const int* __restrict__ node_ids, const int* __restrict__ node_isrel,
    const int* __restrict__ nbr_ids, const int* __restrict__ nbr_isrel,
    const int* __restrict__ nbr_mask, const int* __restrict__ path_ids,
    const int* __restrict__ path_isrel, const int* __restrict__ path_mask,
    const int* __restrict__ edge_ids, const int* __restrict__ edge_isrel,
    const int* __restrict__ edge_mask, float* __restrict__ out) {
  __shared__ Smem sm;
  const int b = blockIdx.x;
  const int d = threadIdx.x;

  const int nid = node_ids[b];
  const float* srow = node_isrel[b] ? rel + (size_t)(nid % R_) * D_
                                    : ent + (size_t)nid * D_;
  const float si_d = srow[d];
  ((uint16_t*)sm.c)[d] = f2bf(si_d);  // row 0; published by pre-dot syncs

  const float ln = ctx_logp<KN_, true>(sm, si_d, ent, rel,
                                       nbr_ids + (size_t)b * KN_,
                                       nbr_isrel + (size_t)b * KN_,
                                       nbr_mask + (size_t)b * KN_);
  const float lp = ctx_logp<KP_, true>(sm, si_d, ent, rel,
                                       path_ids + (size_t)b * KP_,
                                       path_isrel + (size_t)b * KP_,
                                       path_mask + (size_t)b * KP_);
  const float le = ctx_logp<KE_, false>(sm, si_d, ent, rel,
                                        edge_ids + (size_t)b * KE_,
                                        edge_isrel + (size_t)b * KE_,
                                        edge_mask + (size_t)b * KE_);
  if (d == 0) out[b] = -(ln + 0.1f * lp + 0.1f * le);
}

extern "C" void kernel_launch(void* const* d_in, const int* in_sizes, int n_in,
                              void* d_out, int out_size, void* d_ws,
                              size_t ws_size, hipStream_t stream) {
  const float* ent = (const float*)d_in[0];
  const float* rel = (const float*)d_in[1];
  const int* node_ids = (const int*)d_in[2];
  const int* node_isrel = (const int*)d_in[3];
  const int* nbr_ids = (const int*)d_in[4];
  const int* nbr_isrel = (const int*)d_in[5];
  const int* nbr_mask = (const int*)d_in[6];
  const int* path_ids = (const int*)d_in[7];
  const int* path_isrel = (const int*)d_in[8];
  const int* path_mask = (const int*)d_in[9];
  const int* edge_ids = (const int*)d_in[10];
  const int* edge_isrel = (const int*)d_in[11];
  const int* edge_mask = (const int*)d_in[12];
  float* out = (float*)d_out;

  const int B = in_sizes[2];  // node_ids element count = batch
  gake_kernel<<<B, 128, 0, stream>>>(
      ent, rel, node_ids, node_isrel, nbr_ids, nbr_isrel, nbr_mask, path_ids,
      path_isrel, path_mask, edge_ids, edge_isrel, edge_mask, out);
}

// Round 3
// 400.879 us; speedup vs baseline: 1.5688x; 1.5430x over previous
//
#include <hip/hip_runtime.h>
#include <math.h>
#include <stdint.h>

// GakeModel: per-node masked-context log-softmax scoring.
// One 128-thread block (2 waves) per batch element; 3 contexts (K=64,64,16).
//
// R2 -> R3:
//  - valid-row compaction (ballot+scan): gather only ~half the rows, no
//    per-row predication, no dummy loads.  Sum over valid logp needs only
//    (V, sum_s, mx, logZ) -- row identity dead.
//  - float4 gathers: 32 lanes x 16B = 1 row; each wave-instr moves 2 rows
//    (1 KB).  #pragma unroll 8 => deep MLP, 8x fewer vmem instructions.
//  - row-sum via per-lane float4 partials + shfl_xor(32) + Spart in LDS.

constexpr int E_ = 500000;  // entity rows
constexpr int R_ = 1000;    // relation rows
constexpr int D_ = 128;     // embedding dim
constexpr int KN_ = 64, KP_ = 64, KE_ = 16;
constexpr int ROWW = 65;    // uint32 words per tile row (64 data + 1 pad)
constexpr int NROWS = 65;   // row 0 = si, rows 1..64 = compacted context rows

struct Smem {
  uint32_t c[NROWS * ROWW];       // bf16 tile (2 dims per word)
  alignas(16) float S[D_];        // masked row-sum incl. si (fp32)
  alignas(16) float Spart[2][D_]; // per-wave partial row-sums
  float red[8];                   // block-reduce scratch
  int cmeta[64];                  // compacted row index (>=E_ -> relation)
  int Vsh;                        // valid-row count for current context
};

__device__ __forceinline__ float wadd(float v) {
#pragma unroll
  for (int off = 32; off > 0; off >>= 1) v += __shfl_down(v, off, 64);
  return v;  // lane 0 holds the wave sum
}
__device__ __forceinline__ float wmax(float v) {
#pragma unroll
  for (int off = 32; off > 0; off >>= 1) v = fmaxf(v, __shfl_down(v, off, 64));
  return v;
}
__device__ __forceinline__ uint32_t f2bf(float v) {
  const uint32_t u = __float_as_uint(v);
  return (u + 0x7fffu + ((u >> 16) & 1u)) >> 16;  // RNE f32->bf16
}

// Context log-p term.  ACC=true: value valid on all threads.
// ACC=false: only thread 0's value is meaningful (row 0 = si).
template <int K, bool ACC>
__device__ float ctx_logp(Smem& sm, float si_d, float sqsi,
                          const float* __restrict__ ent,
                          const float* __restrict__ rel,
                          const int* __restrict__ ids,
                          const int* __restrict__ isrel,
                          const int* __restrict__ mask) {
  const int d = threadIdx.x;   // 0..127
  const int w = d >> 6;        // wave id
  const int lane = d & 63;
  const int g = lane >> 5;     // row slot within wave-instr (0/1)
  const int cq = lane & 31;    // dim quad: dims 4cq..4cq+3

  __syncthreads();  // (1) previous context's readers are done

  // --- compaction scan (wave 0 only): cmeta[pos] = merged row index -------
  if (w == 0) {
    int m = 0, midx = 0;
    if (lane < K) {
      m = mask[lane];
      const int id = ids[lane];
      midx = isrel[lane] ? E_ + (id % R_) : id;
    }
    const unsigned long long bal = __ballot(m != 0);
    const int pos = __popcll(bal & ((1ull << lane) - 1ull));
    if (m) sm.cmeta[pos] = midx;
    if (lane == 0) sm.Vsh = (int)__popcll(bal);
  }
  __syncthreads();  // (2) cmeta/V published
  const int V = sm.Vsh;

  // --- staging: wave w gathers rows [rs,re), 2 rows per instruction ------
  const int half = (V + 1) >> 1;
  const int rs = w * half;
  const int re = (V < rs + half) ? V : (rs + half);
  float4 Sp = make_float4(0.f, 0.f, 0.f, 0.f);
  float sq = 0.f;
#pragma unroll 8
  for (int r2 = rs; r2 < re; r2 += 2) {
    const int r = r2 + g;
    const bool on = (r < re);
    const int midx = sm.cmeta[on ? r : rs];  // clamp keeps the load safe
    const float* base = (midx >= E_) ? rel + (size_t)(midx - E_) * D_
                                     : ent + (size_t)midx * D_;
    float4 v = *(const float4*)(base + 4 * cq);
    if (!on) { v.x = 0.f; v.y = 0.f; v.z = 0.f; v.w = 0.f; }
    Sp.x += v.x; Sp.y += v.y; Sp.z += v.z; Sp.w += v.w;
    sq += v.x * v.x + v.y * v.y + v.z * v.z + v.w * v.w;
    if (on) {
      uint32_t* rw = sm.c + (size_t)(r + 1) * ROWW;
      rw[2 * cq] = f2bf(v.x) | (f2bf(v.y) << 16);
      rw[2 * cq + 1] = f2bf(v.z) | (f2bf(v.w) << 16);
    }
  }
  // fold the two row-slots (lane l <-> l^32 share the same dim quad)
  Sp.x += __shfl_xor(Sp.x, 32, 64);
  Sp.y += __shfl_xor(Sp.y, 32, 64);
  Sp.z += __shfl_xor(Sp.z, 32, 64);
  Sp.w += __shfl_xor(Sp.w, 32, 64);
  if (lane < 32) *(float4*)&sm.Spart[w][4 * cq] = Sp;
  const float wq = wadd(sq);
  if (lane == 0) sm.red[w] = wq;
  __syncthreads();  // (3) tile, Spart, red[0..1] published

  sm.S[d] = si_d + sm.Spart[0][d] + sm.Spart[1][d];
  const float invn = rsqrtf(sqsi + sm.red[0] + sm.red[1]);
  __syncthreads();  // (4) S published

  // --- scores: thread r owns tile row r (row 0 = si) ----------------------
  float score = 0.f;
  const bool valid = (d <= V);
  if (valid) {
    const uint32_t* row = sm.c + (size_t)d * ROWW;
    const float2* S2 = (const float2*)sm.S;
    float acc = 0.f;
#pragma unroll
    for (int jj = 0; jj < D_ / 2; ++jj) {
      const uint32_t t = row[jj];
      const float2 s2 = S2[jj];
      acc += __uint_as_float(t << 16) * s2.x;          // even dim
      acc += __uint_as_float(t & 0xffff0000u) * s2.y;  // odd dim
    }
    score = acc * invn;
  }

  // --- masked log-softmax over V+1 rows -----------------------------------
  const float wm = wmax(valid ? score : -INFINITY);
  if (lane == 0) sm.red[2 + w] = wm;
  __syncthreads();  // (5) mx partials
  const float mx = fmaxf(sm.red[2], sm.red[3]);

  const float we = wadd(valid ? __expf(score - mx) : 0.f);
  const float ws = wadd(valid ? score : 0.f);
  if (lane == 0) { sm.red[4 + w] = we; sm.red[6 + w] = ws; }
  __syncthreads();  // (6) exp/score sums
  const float logZ = __logf(sm.red[4] + sm.red[5]);
  if (ACC) {
    return (sm.red[6] + sm.red[7]) - (float)(V + 1) * (mx + logZ);
  } else {
    return score - mx - logZ;  // thread 0 holds row 0 (si)
  }
}

__global__ __launch_bounds__(128, 4) void gake_kernel(
    const float* __restrict__ ent, const float* __restrict__ rel,
    const int* __restrict__ node_ids, const int* __restrict__ node_isrel,
    const int* __restrict__ nbr_ids, const int* __restrict__ nbr_isrel,
    const int* __restrict__ nbr_mask, const int* __restrict__ path_ids,
    const int* __restrict__ path_isrel, const int* __restrict__ path_mask,
    const int* __restrict__ edge_ids, const int* __restrict__ edge_isrel,
    const int* __restrict__ edge_mask, float* __restrict__ out) {
  __shared__ Smem sm;
  const int b = blockIdx.x;
  const int d = threadIdx.x;
  const int w = d >> 6;
  const int lane = d & 63;

  const int nid = node_ids[b];
  const float* srow = node_isrel[b] ? rel + (size_t)(nid % R_) * D_
                                    : ent + (size_t)nid * D_;
  const float si_d = srow[d];
  ((uint16_t*)sm.c)[d] = (uint16_t)f2bf(si_d);  // tile row 0

  const float wq = wadd(si_d * si_d);
  if (lane == 0) sm.red[w] = wq;
  __syncthreads();
  const float sqsi = sm.red[0] + sm.red[1];  // every thread keeps a copy

  const float ln = ctx_logp<KN_, true>(sm, si_d, sqsi, ent, rel,
                                       nbr_ids + (size_t)b * KN_,
                                       nbr_isrel + (size_t)b * KN_,
                                       nbr_mask + (size_t)b * KN_);
  const float lp = ctx_logp<KP_, true>(sm, si_d, sqsi, ent, rel,
                                       path_ids + (size_t)b * KP_,
                                       path_isrel + (size_t)b * KP_,
                                       path_mask + (size_t)b * KP_);
  const float le = ctx_logp<KE_, false>(sm, si_d, sqsi, ent, rel,
                                        edge_ids + (size_t)b * KE_,
                                        edge_isrel + (size_t)b * KE_,
                                        edge_mask + (size_t)b * KE_);
  if (d == 0) out[b] = -(ln + 0.1f * lp + 0.1f * le);
}

extern "C" void kernel_launch(void* const* d_in, const int* in_sizes, int n_in,
                              void* d_out, int out_size, void* d_ws,
                              size_t ws_size, hipStream_t stream) {
  const float* ent = (const float*)d_in[0];
  const float* rel = (const float*)d_in[1];
  const int* node_ids = (const int*)d_in[2];
  const int* node_isrel = (const int*)d_in[3];
  const int* nbr_ids = (const int*)d_in[4];
  const int* nbr_isrel = (const int*)d_in[5];
  const int* nbr_mask = (const int*)d_in[6];
  const int* path_ids = (const int*)d_in[7];
  const int* path_isrel = (const int*)d_in[8];
  const int* path_mask = (const int*)d_in[9];
  const int* edge_ids = (const int*)d_in[10];
  const int* edge_isrel = (const int*)d_in[11];
  const int* edge_mask = (const int*)d_in[12];
  float* out = (float*)d_out;

  const int B = in_sizes[2];  // node_ids element count = batch
  gake_kernel<<<B, 128, 0, stream>>>(
      ent, rel, node_ids, node_isrel, nbr_ids, nbr_isrel, nbr_mask, path_ids,
      path_isrel, path_mask, edge_ids, edge_isrel, edge_mask, out);
}